// Round 3
// baseline (799.361 us; speedup 1.0000x reference)
//
#include <hip/hip_runtime.h>
#include <math.h>

// Problem constants (from reference): B=64, S=4096, D=256
#define B_   64
#define S_   4096
#define D_   256
#define CH   32                          // chunks per batch (split-softmax partials)
#define ROWS_PER_CHUNK (S_ / CH)         // 128
#define NWAVE 4
#define ROWS_PER_BLOCK_ITER (NWAVE * 4)  // 16 (4 rows per wave, one per 16-lane quarter)
#define NITER (ROWS_PER_CHUNK / ROWS_PER_BLOCK_ITER)  // 8
#define LN_EPS 1e-3f

typedef float f4 __attribute__((ext_vector_type(4)));

// Fused single kernel: one block per (batch, chunk). 16 lanes per row, 4 rows/wave.
// After writing its split-softmax partial, each block takes a ticket on a
// per-batch counter; the last of the CH blocks for a batch merges the partials
// and writes the final [D] output row (split-K last-block-done pattern).
__global__ __launch_bounds__(256) void pool_fused(
    const float* __restrict__ x, const float* __restrict__ mask,
    const float* __restrict__ gamma, const float* __restrict__ w,
    float* __restrict__ ws_acc, float* __restrict__ ws_m, float* __restrict__ ws_l,
    int* __restrict__ ws_cnt, float* __restrict__ out)
{
    const int blk   = blockIdx.x;
    const int b     = blk / CH;
    const int chunk = blk % CH;
    const int tid   = threadIdx.x;
    const int lane  = tid & 63;
    const int wave  = tid >> 6;
    const int q     = lane >> 4;   // quarter: which of 4 rows this lane works on
    const int t     = lane & 15;   // sublane within the row's 16-lane team

    // gamma*w for this lane's 16 features (beta & dense-bias cancel in softmax)
    f4 gw[4];
    float sgw = 0.0f;
    #pragma unroll
    for (int k = 0; k < 4; ++k) {
        const int d = t * 4 + 64 * k;
        const f4 g4 = *(const f4*)(gamma + d);
        const f4 w4 = *(const f4*)(w + d);
        gw[k] = g4 * w4;
        sgw += gw[k][0] + gw[k][1] + gw[k][2] + gw[k][3];
    }
    #pragma unroll
    for (int off = 8; off > 0; off >>= 1) sgw += __shfl_xor(sgw, off, 64);

    // this lane's row at iteration i: chunk*128 + i*16 + wave*4 + q
    const int row0 = chunk * ROWS_PER_CHUNK + wave * 4 + q;
    const float* xbase = x + ((size_t)b * S_ + row0) * D_ + t * 4;
    const float* mbase = mask + (size_t)b * S_ + row0;

    float m = -3.0e38f;
    float l = 0.0f;
    f4 acc[4];
    #pragma unroll
    for (int k = 0; k < 4; ++k) acc[k] = (f4)0.0f;

    // depth-1 prefetch: 4 KiB of row data in flight across the reduce/softmax.
    // x is read exactly once -> non-temporal (don't thrash L2 with 256 MiB).
    f4 v[4];
    #pragma unroll
    for (int k = 0; k < 4; ++k)
        v[k] = __builtin_nontemporal_load((const f4*)(xbase + 64 * k));
    float msk = mbase[0];

    for (int i = 0; i < NITER; ++i) {
        const int inx = (i + 1 < NITER) ? i + 1 : i;
        f4 vn[4];
        #pragma unroll
        for (int k = 0; k < 4; ++k)
            vn[k] = __builtin_nontemporal_load(
                (const f4*)(xbase + (size_t)inx * ROWS_PER_BLOCK_ITER * D_ + 64 * k));
        const float mskn = mbase[inx * ROWS_PER_BLOCK_ITER];

        // three row reductions over the same data: sum, sumsq, dot(gamma*w)
        float s1 = 0.f, s2 = 0.f, s3 = 0.f;
        #pragma unroll
        for (int k = 0; k < 4; ++k) {
            s1 += v[k][0] + v[k][1] + v[k][2] + v[k][3];
            s2 += v[k][0]*v[k][0] + v[k][1]*v[k][1] + v[k][2]*v[k][2] + v[k][3]*v[k][3];
            s3 += v[k][0]*gw[k][0] + v[k][1]*gw[k][1] + v[k][2]*gw[k][2] + v[k][3]*gw[k][3];
        }
        #pragma unroll
        for (int off = 8; off > 0; off >>= 1) {
            s1 += __shfl_xor(s1, off, 64);
            s2 += __shfl_xor(s2, off, 64);
            s3 += __shfl_xor(s3, off, 64);
        }
        const float mu    = s1 * (1.0f / D_);
        const float var   = s2 * (1.0f / D_) - mu * mu;
        const float rstd  = rsqrtf(var + LN_EPS);
        const float score = rstd * (s3 - mu * sgw) + (1.0f - msk) * -1e9f;

        // online softmax update (identical within each 16-lane quarter)
        const float mnew  = fmaxf(m, score);
        const float scale = __expf(m - mnew);
        const float p     = __expf(score - mnew);
        m = mnew;
        l = l * scale + p;
        #pragma unroll
        for (int k = 0; k < 4; ++k) acc[k] = acc[k] * scale + p * v[k];

        #pragma unroll
        for (int k = 0; k < 4; ++k) v[k] = vn[k];
        msk = mskn;
    }

    // combine the 16 row-groups' partials in LDS
    __shared__ float s_acc[NWAVE * 4][D_];
    __shared__ float s_m[NWAVE * 4];
    __shared__ float s_l[NWAVE * 4];
    const int g = wave * 4 + q;
    #pragma unroll
    for (int k = 0; k < 4; ++k) *(f4*)&s_acc[g][t * 4 + 64 * k] = acc[k];
    if (t == 0) { s_m[g] = m; s_l[g] = l; }
    __syncthreads();

    float M = -3.0e38f;
    #pragma unroll
    for (int gg = 0; gg < 16; ++gg) M = fmaxf(M, s_m[gg]);
    float L = 0.f, a = 0.f;
    #pragma unroll
    for (int gg = 0; gg < 16; ++gg) {
        const float e = __expf(s_m[gg] - M);
        L += e * s_l[gg];
        a += e * s_acc[gg][tid];
    }
    ws_acc[(size_t)blk * D_ + tid] = a;
    if (tid == 0) { ws_m[blk] = M; ws_l[blk] = L; }

    // ---- last-block-done merge (replaces the pass2 dispatch) ----
    __threadfence();                       // release partials (agent scope)
    __shared__ int s_is_last;
    if (tid == 0)
        s_is_last = (atomicAdd(&ws_cnt[b], 1) == CH - 1);
    __syncthreads();
    if (!s_is_last) return;
    __threadfence();                       // acquire other blocks' partials

    float M2 = -3.0e38f;
    #pragma unroll
    for (int c = 0; c < CH; ++c) M2 = fmaxf(M2, ws_m[b * CH + c]);
    float L2 = 0.f, a2 = 0.f;
    #pragma unroll
    for (int c = 0; c < CH; ++c) {
        const float e = __expf(ws_m[b * CH + c] - M2);
        L2 += e * ws_l[b * CH + c];
        a2 += e * ws_acc[((size_t)(b * CH + c)) * D_ + tid];
    }
    out[(size_t)b * D_ + tid] = a2 / L2;
}

extern "C" void kernel_launch(void* const* d_in, const int* in_sizes, int n_in,
                              void* d_out, int out_size, void* d_ws, size_t ws_size,
                              hipStream_t stream) {
    // setup_inputs order: x, mask, gamma, beta, w, b
    const float* x     = (const float*)d_in[0];
    const float* mask  = (const float*)d_in[1];
    const float* gamma = (const float*)d_in[2];
    // d_in[3] = beta : cancels in softmax, unused
    const float* w     = (const float*)d_in[4];
    // d_in[5] = b    : cancels in softmax, unused
    float* out = (float*)d_out;

    // workspace layout: acc[B*CH*D] | m[B*CH] | l[B*CH] | cnt[B]  (~2.02 MB)
    float* ws_acc = (float*)d_ws;
    float* ws_m   = ws_acc + (size_t)B_ * CH * D_;
    float* ws_l   = ws_m + B_ * CH;
    int*   ws_cnt = (int*)(ws_l + B_ * CH);

    // harness poisons d_ws to 0xAA before every launch -> zero the tickets
    hipMemsetAsync(ws_cnt, 0, B_ * sizeof(int), stream);

    pool_fused<<<B_ * CH, 256, 0, stream>>>(x, mask, gamma, w,
                                            ws_acc, ws_m, ws_l, ws_cnt, out);
}

// Round 4
// 342.950 us; speedup vs baseline: 2.3308x; 2.3308x over previous
//
#include <hip/hip_runtime.h>
#include <math.h>

// Problem constants (from reference): B=64, S=4096, D=256
#define B_   64
#define S_   4096
#define D_   256
#define CH   32                          // chunks per batch (split-softmax partials)
#define ROWS_PER_CHUNK (S_ / CH)         // 128
#define NWAVE 4
#define ROWS_PER_BLOCK_ITER (NWAVE * 4)  // 16 (4 rows per wave, one per 16-lane quarter)
#define NITER (ROWS_PER_CHUNK / ROWS_PER_BLOCK_ITER)  // 8
#define LN_EPS 1e-3f

typedef float f4 __attribute__((ext_vector_type(4)));

// Pass 1: one block per (batch, chunk). 16 lanes per row, 4 rows per wave.
// Lane (q = lane>>4, t = lane&15) owns row r+q, features d = t*4 + 64*k (k=0..3)
// -> each float4 load instr = 4 rows x 256 B contiguous segments (ideal coalescing),
// score reduction = 4-round butterfly (offsets 8,4,2,1): 3 ds_swizzle per row.
//
// NOTE (R3 lesson): do NOT fuse the merge with per-block __threadfence() —
// agent-scope fences emit buffer_wbl2 (L2 writeback) per block; 2048 blocks
// serialize on L2 coherence traffic => 530 µs kernel at 3% HBM BW.
__global__ __launch_bounds__(256) void pool_pass1(
    const float* __restrict__ x, const float* __restrict__ mask,
    const float* __restrict__ gamma, const float* __restrict__ w,
    float* __restrict__ ws_acc, float* __restrict__ ws_m, float* __restrict__ ws_l)
{
    const int blk   = blockIdx.x;
    const int b     = blk / CH;
    const int chunk = blk % CH;
    const int tid   = threadIdx.x;
    const int lane  = tid & 63;
    const int wave  = tid >> 6;
    const int q     = lane >> 4;   // quarter: which of 4 rows this lane works on
    const int t     = lane & 15;   // sublane within the row's 16-lane team

    // gamma*w for this lane's 16 features (beta & dense-bias cancel in softmax)
    f4 gw[4];
    float sgw = 0.0f;
    #pragma unroll
    for (int k = 0; k < 4; ++k) {
        const int d = t * 4 + 64 * k;
        const f4 g4 = *(const f4*)(gamma + d);
        const f4 w4 = *(const f4*)(w + d);
        gw[k] = g4 * w4;
        sgw += gw[k][0] + gw[k][1] + gw[k][2] + gw[k][3];
    }
    #pragma unroll
    for (int off = 8; off > 0; off >>= 1) sgw += __shfl_xor(sgw, off, 64);

    // this lane's row at iteration i: chunk*128 + i*16 + wave*4 + q
    const int row0 = chunk * ROWS_PER_CHUNK + wave * 4 + q;
    const float* xbase = x + ((size_t)b * S_ + row0) * D_ + t * 4;
    const float* mbase = mask + (size_t)b * S_ + row0;

    float m = -3.0e38f;
    float l = 0.0f;
    f4 acc[4];
    #pragma unroll
    for (int k = 0; k < 4; ++k) acc[k] = (f4)0.0f;

    // depth-1 prefetch: 4 KiB of row data in flight across the reduce/softmax.
    // x is read exactly once -> non-temporal (evict-first; no reuse to protect).
    f4 v[4];
    #pragma unroll
    for (int k = 0; k < 4; ++k)
        v[k] = __builtin_nontemporal_load((const f4*)(xbase + 64 * k));
    float msk = mbase[0];

    for (int i = 0; i < NITER; ++i) {
        const int inx = (i + 1 < NITER) ? i + 1 : i;
        f4 vn[4];
        #pragma unroll
        for (int k = 0; k < 4; ++k)
            vn[k] = __builtin_nontemporal_load(
                (const f4*)(xbase + (size_t)inx * ROWS_PER_BLOCK_ITER * D_ + 64 * k));
        const float mskn = mbase[inx * ROWS_PER_BLOCK_ITER];

        // three row reductions over the same data: sum, sumsq, dot(gamma*w)
        float s1 = 0.f, s2 = 0.f, s3 = 0.f;
        #pragma unroll
        for (int k = 0; k < 4; ++k) {
            s1 += v[k][0] + v[k][1] + v[k][2] + v[k][3];
            s2 += v[k][0]*v[k][0] + v[k][1]*v[k][1] + v[k][2]*v[k][2] + v[k][3]*v[k][3];
            s3 += v[k][0]*gw[k][0] + v[k][1]*gw[k][1] + v[k][2]*gw[k][2] + v[k][3]*gw[k][3];
        }
        #pragma unroll
        for (int off = 8; off > 0; off >>= 1) {
            s1 += __shfl_xor(s1, off, 64);
            s2 += __shfl_xor(s2, off, 64);
            s3 += __shfl_xor(s3, off, 64);
        }
        const float mu    = s1 * (1.0f / D_);
        const float var   = s2 * (1.0f / D_) - mu * mu;
        const float rstd  = rsqrtf(var + LN_EPS);
        const float score = rstd * (s3 - mu * sgw) + (1.0f - msk) * -1e9f;

        // online softmax update (identical within each 16-lane quarter)
        const float mnew  = fmaxf(m, score);
        const float scale = __expf(m - mnew);
        const float p     = __expf(score - mnew);
        m = mnew;
        l = l * scale + p;
        #pragma unroll
        for (int k = 0; k < 4; ++k) acc[k] = acc[k] * scale + p * v[k];

        #pragma unroll
        for (int k = 0; k < 4; ++k) v[k] = vn[k];
        msk = mskn;
    }

    // combine the 16 row-groups' partials in LDS
    __shared__ float s_acc[NWAVE * 4][D_];
    __shared__ float s_m[NWAVE * 4];
    __shared__ float s_l[NWAVE * 4];
    const int g = wave * 4 + q;
    #pragma unroll
    for (int k = 0; k < 4; ++k) *(f4*)&s_acc[g][t * 4 + 64 * k] = acc[k];
    if (t == 0) { s_m[g] = m; s_l[g] = l; }
    __syncthreads();

    float M = -3.0e38f;
    #pragma unroll
    for (int gg = 0; gg < 16; ++gg) M = fmaxf(M, s_m[gg]);
    float L = 0.f, a = 0.f;
    #pragma unroll
    for (int gg = 0; gg < 16; ++gg) {
        const float e = __expf(s_m[gg] - M);
        L += e * s_l[gg];
        a += e * s_acc[gg][tid];
    }
    ws_acc[(size_t)blk * D_ + tid] = a;
    if (tid == 0) { ws_m[blk] = M; ws_l[blk] = L; }
}

// Pass 2: merge the CH partials per batch. One block per batch, one thread per d.
__global__ __launch_bounds__(256) void pool_pass2(
    const float* __restrict__ ws_acc, const float* __restrict__ ws_m,
    const float* __restrict__ ws_l, float* __restrict__ out)
{
    const int b = blockIdx.x;
    const int d = threadIdx.x;

    float M = -3.0e38f;
    #pragma unroll
    for (int c = 0; c < CH; ++c) M = fmaxf(M, ws_m[b * CH + c]);

    float L = 0.0f, a = 0.0f;
    #pragma unroll
    for (int c = 0; c < CH; ++c) {
        const float e = __expf(ws_m[b * CH + c] - M);
        L += e * ws_l[b * CH + c];
        a += e * ws_acc[((size_t)(b * CH + c)) * D_ + d];
    }
    out[(size_t)b * D_ + d] = a / L;
}

extern "C" void kernel_launch(void* const* d_in, const int* in_sizes, int n_in,
                              void* d_out, int out_size, void* d_ws, size_t ws_size,
                              hipStream_t stream) {
    // setup_inputs order: x, mask, gamma, beta, w, b
    const float* x     = (const float*)d_in[0];
    const float* mask  = (const float*)d_in[1];
    const float* gamma = (const float*)d_in[2];
    // d_in[3] = beta : cancels in softmax, unused
    const float* w     = (const float*)d_in[4];
    // d_in[5] = b    : cancels in softmax, unused
    float* out = (float*)d_out;

    // workspace layout: acc[B*CH*D] | m[B*CH] | l[B*CH]  (~2.02 MB)
    float* ws_acc = (float*)d_ws;
    float* ws_m   = ws_acc + (size_t)B_ * CH * D_;
    float* ws_l   = ws_m + B_ * CH;

    pool_pass1<<<B_ * CH, 256, 0, stream>>>(x, mask, gamma, w, ws_acc, ws_m, ws_l);
    pool_pass2<<<B_, 256, 0, stream>>>(ws_acc, ws_m, ws_l, out);
}